// Round 1
// baseline (191516.541 us; speedup 1.0000x reference)
//
#include <hip/hip_runtime.h>
#include <math.h>

#define TT   100000
#define HH   74
#define G4   296          // 4*H gate rows per layer
#define KW   76           // K padded to 19*4 for float4 LDS reads
#define SLOT 80           // ring/LDS slot stride in floats (320 B, 16B aligned)
#define NT   384          // 296 row threads + wave5 (320..383) prefetch

__global__ void init_ctrl(unsigned* ctrl) {
    if (threadIdx.x < 128) ctrl[threadIdx.x] = 0u;   // zero counters (ws is poisoned 0xAA)
}

__launch_bounds__(NT)
__global__ void lstm_pipe(const float* __restrict__ seasons,
                          const float* __restrict__ W_ih,
                          const float* __restrict__ W_hh,
                          const float* __restrict__ b_ih,
                          const float* __restrict__ b_hh,
                          const float* __restrict__ W_lin,
                          const float* __restrict__ b_lin,
                          float* __restrict__ out,
                          unsigned* ctrl,
                          float* ring0, float* ring1, int C)
{
    const int stage = blockIdx.x;     // one workgroup per LSTM layer (pipeline stage)
    const int tid   = threadIdx.x;
    const int row   = tid;

    __shared__ __align__(16) float xbuf[2][SLOT];  // double-buffered layer input
    __shared__ __align__(16) float hbuf[SLOT];     // this layer's h_{t-1}, broadcast
    __shared__ float gbuf[G4];                     // activated gates

    unsigned* cnt_out  = ctrl + stage * 32;                              // 128B apart
    unsigned* cnt_in   = ctrl + (stage > 0 ? (stage - 1) * 32 : 0);
    unsigned* cnt_down = ctrl + (stage < 2 ? (stage + 1) * 32 : 0);
    float* ring_out = (stage == 0) ? ring0 : ring1;
    float* ring_in  = (stage == 1) ? ring0 : ring1;

    // ---- LDS init (h_{-1} = 0, zero float4 pads) ----
    if (tid < SLOT) hbuf[tid] = 0.0f;
    if (tid >= SLOT && tid < SLOT + 2*(SLOT-HH)) {
        int k = tid - SLOT;
        xbuf[k/(SLOT-HH)][HH + k%(SLOT-HH)] = 0.0f;
    }

    // ---- weights into registers: one gate-row per thread (148 VGPRs) ----
    const bool isRow = (row < G4);
    float wih[KW], whh[KW];
    float bias = 0.0f;
    if (isRow) {
        const float* si = W_ih + (size_t)(stage*G4 + row) * HH;  // rows are 8B aligned
        const float* sh = W_hh + (size_t)(stage*G4 + row) * HH;
        #pragma unroll
        for (int k = 0; k < HH/2; ++k) {
            float2 a = *(const float2*)(si + 2*k);
            float2 b = *(const float2*)(sh + 2*k);
            wih[2*k] = a.x; wih[2*k+1] = a.y;
            whh[2*k] = b.x; whh[2*k+1] = b.y;
        }
        wih[74] = wih[75] = 0.0f;
        whh[74] = whh[75] = 0.0f;
        bias = b_ih[stage*G4 + row] + b_hh[stage*G4 + row];
    }

    float wl0 = 0.f, wl1 = 0.f, blin = 0.f;
    if (stage == 2 && tid < 64) {                 // final linear, wave0 only
        wl0 = W_lin[tid];
        wl1 = (tid < HH-64) ? W_lin[64 + tid] : 0.0f;
        blin = b_lin[0];
    }

    __syncthreads();

    // ---- prologue: fetch x_0 into xbuf[0] (wave5) ----
    if (tid >= 320) {
        const int lane = tid - 320;
        if (stage == 0) {
            xbuf[0][lane] = seasons[lane];
            if (lane < HH-64) xbuf[0][64+lane] = seasons[64+lane];
        } else {
            while (__hip_atomic_load(cnt_in, __ATOMIC_ACQUIRE, __HIP_MEMORY_SCOPE_AGENT) < 1u) {}
            xbuf[0][lane] = __hip_atomic_load(ring_in + lane, __ATOMIC_RELAXED, __HIP_MEMORY_SCOPE_AGENT);
            if (lane < HH-64)
                xbuf[0][64+lane] = __hip_atomic_load(ring_in + 64 + lane, __ATOMIC_RELAXED, __HIP_MEMORY_SCOPE_AGENT);
        }
    }
    __syncthreads();

    float c = 0.0f;            // persistent cell state (tid < 74)
    float pf = 0.0f;           // L2 touch-prefetch sink
    unsigned cons = 0;         // cached downstream progress (flow control)
    int slot_w = 0;            // t     % C
    int slot_r = 1 % C;        // (t+1) % C

    for (int t = 0; t < TT; ++t) {
        const int b = t & 1;

        // ---- Phase A: gates (row threads) | input prefetch (wave5) ----
        if (isRow) {
            const float4* xv = (const float4*)xbuf[b];
            const float4* hv = (const float4*)hbuf;
            float a0 = bias, a1 = 0.f, a2 = 0.f, a3 = 0.f;
            #pragma unroll
            for (int k = 0; k < KW/4; ++k) {
                float4 x4 = xv[k];           // uniform-address broadcast ds_read_b128
                a0 += wih[4*k+0] * x4.x;
                a1 += wih[4*k+1] * x4.y;
                a2 += wih[4*k+2] * x4.z;
                a3 += wih[4*k+3] * x4.w;
            }
            #pragma unroll
            for (int k = 0; k < KW/4; ++k) {
                float4 h4 = hv[k];
                a0 += whh[4*k+0] * h4.x;
                a1 += whh[4*k+1] * h4.y;
                a2 += whh[4*k+2] * h4.z;
                a3 += whh[4*k+3] * h4.w;
            }
            float gsum = (a0 + a1) + (a2 + a3);
            const bool isG = (row >= 2*HH) && (row < 3*HH);
            float arg = isG ? 2.0f * gsum : gsum;          // tanh(x) = 2*sigm(2x)-1
            float s = 1.0f / (1.0f + expf(-arg));          // expf overflow -> s=0 (safe)
            gbuf[row] = isG ? (2.0f*s - 1.0f) : s;
        } else if (tid >= 320) {
            if (t + 1 < TT) {
                const int lane = tid - 320;
                const int nb = b ^ 1;
                if (stage == 0) {
                    const float* xs = seasons + (size_t)(t+1) * HH;
                    float v0 = xs[lane];
                    float v1 = (lane < HH-64) ? xs[64+lane] : 0.0f;
                    if (t + 8 < TT) pf += seasons[(size_t)(t+8)*HH + lane]; // L2 warm-up
                    xbuf[nb][lane] = v0;
                    if (lane < HH-64) xbuf[nb][64+lane] = v1;
                } else {
                    while (__hip_atomic_load(cnt_in, __ATOMIC_ACQUIRE, __HIP_MEMORY_SCOPE_AGENT) < (unsigned)(t+2)) {}
                    const float* rs = ring_in + (size_t)slot_r * SLOT;
                    float v0 = __hip_atomic_load(rs + lane, __ATOMIC_RELAXED, __HIP_MEMORY_SCOPE_AGENT);
                    float v1 = (lane < HH-64) ? __hip_atomic_load(rs + 64 + lane, __ATOMIC_RELAXED, __HIP_MEMORY_SCOPE_AGENT) : 0.0f;
                    xbuf[nb][lane] = v0;
                    if (lane < HH-64) xbuf[nb][64+lane] = v1;
                }
            }
        }
        __syncthreads();

        // ---- Phase B: cell update (tid < 74) + ring publish ----
        if (tid < HH) {
            float iv = gbuf[tid];
            float fv = gbuf[HH + tid];
            float gv = gbuf[2*HH + tid];
            float ov = gbuf[3*HH + tid];
            c = fv * c + iv * gv;
            float e  = expf(-2.0f * fabsf(c));             // overflow-safe tanh
            float th = copysignf((1.0f - e) / (1.0f + e), c);
            float h  = ov * th;
            hbuf[tid] = h;
            if (stage < 2) {
                while ((int)t - (int)cons >= C - 8)        // ring flow control (rare)
                    cons = __hip_atomic_load(cnt_down, __ATOMIC_RELAXED, __HIP_MEMORY_SCOPE_AGENT);
                __hip_atomic_store(ring_out + (size_t)slot_w * SLOT + tid, h,
                                   __ATOMIC_RELAXED, __HIP_MEMORY_SCOPE_AGENT);
            }
        }
        __syncthreads();   // drains vmcnt before barrier -> data stores complete

        if (tid == 0)      // publish step t done (also serves as progress for upstream)
            __hip_atomic_store(cnt_out, (unsigned)(t+1), __ATOMIC_RELEASE, __HIP_MEMORY_SCOPE_AGENT);

        // ---- final linear + relu (stage 2, wave0) ----
        if (stage == 2 && tid < 64) {
            float p = wl0 * hbuf[tid];
            if (tid < HH-64) p += wl1 * hbuf[64 + tid];
            #pragma unroll
            for (int m = 32; m >= 1; m >>= 1)
                p += __shfl_xor(p, m, 64);
            if (tid == 0) out[t] = fmaxf(p + blin, 0.0f);
        }

        slot_w = (slot_w + 1 == C) ? 0 : slot_w + 1;
        slot_r = (slot_r + 1 == C) ? 0 : slot_r + 1;
    }
    asm volatile("" :: "v"(pf));   // keep prefetch sum live without a data-dependent store
}

extern "C" void kernel_launch(void* const* d_in, const int* in_sizes, int n_in,
                              void* d_out, int out_size, void* d_ws, size_t ws_size,
                              hipStream_t stream)
{
    (void)in_sizes; (void)n_in; (void)out_size;
    const float* seasons = (const float*)d_in[0];
    const float* W_ih  = (const float*)d_in[1];
    const float* W_hh  = (const float*)d_in[2];
    const float* b_ih  = (const float*)d_in[3];
    const float* b_hh  = (const float*)d_in[4];
    const float* W_lin = (const float*)d_in[5];
    const float* b_lin = (const float*)d_in[6];
    float* out = (float*)d_out;

    unsigned* ctrl = (unsigned*)d_ws;
    float* ring0 = (float*)((char*)d_ws + 1024);
    long avail  = (long)ws_size - 1024;
    long cslots = avail / (long)(2 * SLOT * sizeof(float));
    int  C = (int)(cslots < TT ? cslots : TT);
    if (C < 16) C = 16;
    float* ring1 = ring0 + (size_t)C * SLOT;

    hipLaunchKernelGGL(init_ctrl, dim3(1), dim3(128), 0, stream, ctrl);
    hipLaunchKernelGGL(lstm_pipe, dim3(3), dim3(NT), 0, stream,
                       seasons, W_ih, W_hh, b_ih, b_hh, W_lin, b_lin,
                       out, ctrl, ring0, ring1, C);
}

// Round 2
// 134800.281 us; speedup vs baseline: 1.4207x; 1.4207x over previous
//
#include <hip/hip_runtime.h>
#include <math.h>

#define TT   100000
#define HH   74
#define G4   296          // 4*H gate rows per layer
#define KW   76           // K padded to 19*4 for float4 LDS reads
#define SLOT 80           // ring/LDS slot stride in floats (320 B, 16B aligned)
#define NT   384          // 296 row threads + wave5 (320..383) helper
#define W5   320

__global__ void init_ctrl(unsigned* ctrl) {
    if (threadIdx.x < 128) ctrl[threadIdx.x] = 0u;   // ws is poisoned 0xAA each launch
}

__launch_bounds__(NT, 2)   // min 2 waves/EU -> 256-VGPR budget: weights MUST stay in regs
__global__ void lstm_pipe(const float* __restrict__ seasons,
                          const float* __restrict__ W_ih,
                          const float* __restrict__ W_hh,
                          const float* __restrict__ b_ih,
                          const float* __restrict__ b_hh,
                          const float* __restrict__ W_lin,
                          const float* __restrict__ b_lin,
                          float* __restrict__ out,
                          unsigned* ctrl,
                          float* ring0, float* ring1, int C)
{
    const int stage = blockIdx.x;     // one workgroup per LSTM layer (pipeline stage)
    const int tid   = threadIdx.x;
    const int row   = tid;

    __shared__ __align__(16) float xbuf[2][SLOT];  // double-buffered layer input
    __shared__ __align__(16) float hbuf[SLOT];     // this layer's h_{t-1}
    __shared__ float gbuf[G4];                     // activated gates

    unsigned* cnt_out  = ctrl + stage * 32;
    unsigned* cnt_in   = ctrl + (stage > 0 ? (stage - 1) * 32 : 0);
    unsigned* cnt_down = ctrl + (stage < 2 ? (stage + 1) * 32 : 0);
    float* ring_out = (stage == 0) ? ring0 : ring1;
    float* ring_in  = (stage == 1) ? ring0 : ring1;

    // ---- LDS init: h_{-1}=0, zero the float4 pads of xbuf ----
    if (tid < SLOT) hbuf[tid] = 0.0f;
    if (tid >= SLOT && tid < SLOT + 2*(SLOT-HH)) {
        int k = tid - SLOT;
        xbuf[k/(SLOT-HH)][HH + k%(SLOT-HH)] = 0.0f;
    }

    // ---- weights into registers: one gate-row per thread ----
    const bool isRow = (row < G4);
    float wih[KW], whh[KW];
    float bias = 0.0f;
    if (isRow) {
        const float* si = W_ih + (size_t)(stage*G4 + row) * HH;
        const float* sh = W_hh + (size_t)(stage*G4 + row) * HH;
        const bool isG = (row >= 2*HH) && (row < 3*HH);
        const float sc = isG ? 2.0f : 1.0f;        // fold tanh's 2x into weights
        #pragma unroll
        for (int k = 0; k < HH/2; ++k) {
            float2 a = *(const float2*)(si + 2*k);
            float2 b = *(const float2*)(sh + 2*k);
            wih[2*k] = sc*a.x; wih[2*k+1] = sc*a.y;
            whh[2*k] = sc*b.x; whh[2*k+1] = sc*b.y;
        }
        wih[74] = wih[75] = 0.0f;
        whh[74] = whh[75] = 0.0f;
        bias = sc * (b_ih[stage*G4 + row] + b_hh[stage*G4 + row]);
    }

    float wl0 = 0.f, wl1 = 0.f, blin = 0.f;
    if (stage == 2 && tid >= W5) {                 // final linear lives on wave5
        int lane = tid - W5;
        wl0 = W_lin[lane];
        wl1 = (lane < HH-64) ? W_lin[64 + lane] : 0.0f;
        blin = b_lin[0];
    }

    __syncthreads();

    // ---- prologue (wave5): xbuf[0] = x(0); xr = x(1) in regs; first cnt sample ----
    float xr0 = 0.f, xr1 = 0.f;
    unsigned cin = 0, cons = 0;
    if (tid >= W5) {
        const int lane = tid - W5;
        if (stage == 0) {
            xbuf[0][lane] = seasons[lane];
            if (lane < HH-64) xbuf[0][64+lane] = seasons[64+lane];
            xr0 = seasons[HH + lane];
            if (lane < HH-64) xr1 = seasons[HH + 64 + lane];
        } else {
            do { cin = __hip_atomic_load(cnt_in, __ATOMIC_ACQUIRE, __HIP_MEMORY_SCOPE_AGENT); }
            while (cin < 2u);
            xbuf[0][lane] = __hip_atomic_load(ring_in + lane, __ATOMIC_RELAXED, __HIP_MEMORY_SCOPE_AGENT);
            if (lane < HH-64)
                xbuf[0][64+lane] = __hip_atomic_load(ring_in + 64 + lane, __ATOMIC_RELAXED, __HIP_MEMORY_SCOPE_AGENT);
            const float* rs = ring_in + (size_t)(1 % C) * SLOT;
            xr0 = __hip_atomic_load(rs + lane, __ATOMIC_RELAXED, __HIP_MEMORY_SCOPE_AGENT);
            if (lane < HH-64)
                xr1 = __hip_atomic_load(rs + 64 + lane, __ATOMIC_RELAXED, __HIP_MEMORY_SCOPE_AGENT);
        }
    }
    __syncthreads();

    float c = 0.0f;            // persistent cell state (tid < 74)
    float pf = 0.0f;           // L2 touch-prefetch sink

    for (int t = 0; t < TT; ++t) {
        // ================= Phase A =================
        if (isRow) {
            const float4* xv = (const float4*)xbuf[t & 1];
            const float4* hv = (const float4*)hbuf;
            float a0 = bias, a1 = 0.f, a2 = 0.f, a3 = 0.f;
            #pragma unroll
            for (int k = 0; k < KW/4; ++k) {
                float4 x4 = xv[k];                 // uniform-address broadcast b128
                a0 += wih[4*k+0] * x4.x;
                a1 += wih[4*k+1] * x4.y;
                a2 += wih[4*k+2] * x4.z;
                a3 += wih[4*k+3] * x4.w;
            }
            #pragma unroll
            for (int k = 0; k < KW/4; ++k) {
                float4 h4 = hv[k];
                a0 += whh[4*k+0] * h4.x;
                a1 += whh[4*k+1] * h4.y;
                a2 += whh[4*k+2] * h4.z;
                a3 += whh[4*k+3] * h4.w;
            }
            float gsum = (a0 + a1) + (a2 + a3);
            float s = __builtin_amdgcn_rcpf(1.0f + __expf(-gsum));   // sigmoid
            const bool isG = (row >= 2*HH) && (row < 3*HH);          // tanh = 2*sigm(2x)-1
            gbuf[row] = isG ? fmaf(2.0f, s, -1.0f) : s;
        } else if (tid >= W5) {
            const int lane = tid - W5;
            // ---- ring store h(t-1) + publish (stages 0,1); linear (stage 2) ----
            if (t > 0) {
                if (stage < 2) {
                    float h0 = hbuf[lane];
                    float h1 = (lane < HH-64) ? hbuf[64+lane] : 0.0f;
                    while ((long)t - (long)cons > (long)(C - 8))     // flow control (rare)
                        cons = __hip_atomic_load(cnt_down, __ATOMIC_RELAXED, __HIP_MEMORY_SCOPE_AGENT);
                    float* rs = ring_out + (size_t)((t-1) % C) * SLOT;
                    __hip_atomic_store(rs + lane, h0, __ATOMIC_RELAXED, __HIP_MEMORY_SCOPE_AGENT);
                    if (lane < HH-64)
                        __hip_atomic_store(rs + 64 + lane, h1, __ATOMIC_RELAXED, __HIP_MEMORY_SCOPE_AGENT);
                    if (lane == 0)   // release: waits this wave's vmcnt -> stores visible first
                        __hip_atomic_store(cnt_out, (unsigned)t, __ATOMIC_RELEASE, __HIP_MEMORY_SCOPE_AGENT);
                } else {
                    if (lane == 0)   // progress only (stage1 flow control)
                        __hip_atomic_store(cnt_out, (unsigned)t, __ATOMIC_RELAXED, __HIP_MEMORY_SCOPE_AGENT);
                    float p = wl0 * hbuf[lane];
                    if (lane < HH-64) p += wl1 * hbuf[64 + lane];
                    #pragma unroll
                    for (int m = 32; m >= 1; m >>= 1)
                        p += __shfl_xor(p, m, 64);
                    if (lane == 0) out[t-1] = fmaxf(p + blin, 0.0f);
                }
            }
            // ---- write x(t+1) from regs (loaded one full step ago) ----
            const int nb = (t + 1) & 1;
            xbuf[nb][lane] = xr0;
            if (lane < HH-64) xbuf[nb][64+lane] = xr1;
            // ---- issue loads for x(t+2): latency spans a whole step ----
            if (t + 2 < TT) {
                if (stage == 0) {
                    const float* xs = seasons + (size_t)(t+2) * HH;
                    xr0 = xs[lane];
                    if (lane < HH-64) xr1 = xs[64+lane];
                    if (t + 16 < TT) pf += seasons[(size_t)(t+16)*HH + lane];
                } else {
                    if (cin < (unsigned)(t + 3)) {                   // look-behind check
                        do { cin = __hip_atomic_load(cnt_in, __ATOMIC_ACQUIRE, __HIP_MEMORY_SCOPE_AGENT); }
                        while (cin < (unsigned)(t + 3));
                    }
                    const float* rs2 = ring_in + (size_t)((t+2) % C) * SLOT;
                    xr0 = __hip_atomic_load(rs2 + lane, __ATOMIC_RELAXED, __HIP_MEMORY_SCOPE_AGENT);
                    if (lane < HH-64)
                        xr1 = __hip_atomic_load(rs2 + 64 + lane, __ATOMIC_RELAXED, __HIP_MEMORY_SCOPE_AGENT);
                    // refresh look-behind sample; value consumed next iteration
                    cin = __hip_atomic_load(cnt_in, __ATOMIC_RELAXED, __HIP_MEMORY_SCOPE_AGENT);
                }
            }
        }
        __syncthreads();   // barrier1: gates ready, x(t+1) staged

        // ================= Phase B =================
        if (tid < HH) {
            float iv = gbuf[tid];
            float fv = gbuf[HH + tid];
            float gv = gbuf[2*HH + tid];
            float ov = gbuf[3*HH + tid];
            c = fmaf(fv, c, iv * gv);
            float e  = __expf(-2.0f * fabsf(c));                     // overflow-safe tanh
            float th = copysignf((1.0f - e) * __builtin_amdgcn_rcpf(1.0f + e), c);
            hbuf[tid] = ov * th;
        }
        __syncthreads();   // barrier2: h(t) ready
    }

    // ---- epilogue: h(TT-1) ----
    if (tid >= W5) {
        const int lane = tid - W5;
        if (stage < 2) {
            float h0 = hbuf[lane];
            float h1 = (lane < HH-64) ? hbuf[64+lane] : 0.0f;
            float* rs = ring_out + (size_t)((TT-1) % C) * SLOT;
            __hip_atomic_store(rs + lane, h0, __ATOMIC_RELAXED, __HIP_MEMORY_SCOPE_AGENT);
            if (lane < HH-64)
                __hip_atomic_store(rs + 64 + lane, h1, __ATOMIC_RELAXED, __HIP_MEMORY_SCOPE_AGENT);
            if (lane == 0)
                __hip_atomic_store(cnt_out, (unsigned)TT, __ATOMIC_RELEASE, __HIP_MEMORY_SCOPE_AGENT);
        } else {
            float p = wl0 * hbuf[lane];
            if (lane < HH-64) p += wl1 * hbuf[64 + lane];
            #pragma unroll
            for (int m = 32; m >= 1; m >>= 1)
                p += __shfl_xor(p, m, 64);
            if (lane == 0) out[TT-1] = fmaxf(p + blin, 0.0f);
        }
    }
    asm volatile("" :: "v"(pf));   // keep prefetch sum live
}

extern "C" void kernel_launch(void* const* d_in, const int* in_sizes, int n_in,
                              void* d_out, int out_size, void* d_ws, size_t ws_size,
                              hipStream_t stream)
{
    (void)in_sizes; (void)n_in; (void)out_size;
    const float* seasons = (const float*)d_in[0];
    const float* W_ih  = (const float*)d_in[1];
    const float* W_hh  = (const float*)d_in[2];
    const float* b_ih  = (const float*)d_in[3];
    const float* b_hh  = (const float*)d_in[4];
    const float* W_lin = (const float*)d_in[5];
    const float* b_lin = (const float*)d_in[6];
    float* out = (float*)d_out;

    unsigned* ctrl = (unsigned*)d_ws;
    float* ring0 = (float*)((char*)d_ws + 1024);
    long avail  = (long)ws_size - 1024;
    long cslots = avail / (long)(2 * SLOT * sizeof(float));
    int  C = (int)(cslots < TT ? cslots : TT);
    if (C < 16) C = 16;
    float* ring1 = ring0 + (size_t)C * SLOT;

    hipLaunchKernelGGL(init_ctrl, dim3(1), dim3(128), 0, stream, ctrl);
    hipLaunchKernelGGL(lstm_pipe, dim3(3), dim3(NT), 0, stream,
                       seasons, W_ih, W_hh, b_ih, b_hh, W_lin, b_lin,
                       out, ctrl, ring0, ring1, C);
}

// Round 4
// 114382.556 us; speedup vs baseline: 1.6744x; 1.1785x over previous
//
#include <hip/hip_runtime.h>
#include <math.h>

#define TT   100000
#define HH   74
#define G4   296          // 4*H gate rows per layer
#define KH   40           // per-thread K half (padded 74 -> 80)
#define SLOT 80           // ring/LDS slot stride in floats (320 B, 16B aligned)
#define NT   704          // 10 row-waves (640 = 320 rows x 2 halves) + helper wave
#define W5   640

__global__ void init_ctrl(unsigned* ctrl) {
    if (threadIdx.x < 128) ctrl[threadIdx.x] = 0u;   // ws is poisoned 0xAA each launch
}

__launch_bounds__(NT, 2)
__global__ void lstm_pipe(const float* __restrict__ seasons,
                          const float* __restrict__ W_ih,
                          const float* __restrict__ W_hh,
                          const float* __restrict__ b_ih,
                          const float* __restrict__ b_hh,
                          const float* __restrict__ W_lin,
                          const float* __restrict__ b_lin,
                          float* __restrict__ out,
                          unsigned* ctrl,
                          float* ring0, float* ring1, int C)
{
    const int stage = blockIdx.x;     // one workgroup per LSTM layer (pipeline stage)
    const int tid   = threadIdx.x;

    __shared__ __align__(16) float xbuf[2][SLOT];  // double-buffered layer input
    __shared__ __align__(16) float hbuf[SLOT];     // this layer's h_{t-1}
    __shared__ float gbuf[G4];                     // activated gates

    unsigned* cnt_out  = ctrl + stage * 32;
    unsigned* cnt_in   = ctrl + (stage > 0 ? (stage - 1) * 32 : 0);
    unsigned* cnt_down = ctrl + (stage < 2 ? (stage + 1) * 32 : 0);
    float* ring_out = (stage == 0) ? ring0 : ring1;
    float* ring_in  = (stage == 1) ? ring0 : ring1;

    // ---- LDS init: h_{-1}=0 (incl. pad), zero the pads of xbuf ----
    if (tid < SLOT) hbuf[tid] = 0.0f;
    if (tid >= SLOT && tid < SLOT + 2*(SLOT-HH)) {
        int k = tid - SLOT;
        xbuf[k/(SLOT-HH)][HH + k%(SLOT-HH)] = 0.0f;
    }

    // ---- row mapping: lane pair per row; each thread holds ONE K-half ----
    // (80 weight floats/thread -> no spill even at a 120-VGPR budget)
    const bool isRowT = (tid < W5);
    const int  row  = (tid >> 6) * 32 + ((tid & 63) >> 1);   // 0..319 (>=296 pad)
    const int  half = tid & 1;                               // k-half
    const int  wrow = (row < G4) ? row : (G4 - 1);           // clamp for safe loads

    float wih[KH], whh[KH];
    float bias = 0.0f;
    if (isRowT) {
        const bool  isG = (wrow >= 2*HH) && (wrow < 3*HH);   // g-gate: fold tanh 2x
        const float sc  = isG ? 2.0f : 1.0f;
        const float* si = W_ih + (size_t)(stage*G4 + wrow) * HH;
        const float* sh = W_hh + (size_t)(stage*G4 + wrow) * HH;
        #pragma unroll
        for (int j = 0; j < KH; ++j) {
            int k  = half*KH + j;
            int kk = (k < HH) ? k : 0;                       // clamped addr, masked value
            float vi = si[kk], vh = sh[kk];
            wih[j] = (k < HH) ? sc*vi : 0.0f;
            whh[j] = (k < HH) ? sc*vh : 0.0f;
        }
        if (half == 0)
            bias = sc * (b_ih[stage*G4 + wrow] + b_hh[stage*G4 + wrow]);
    }

    float wl0 = 0.f, wl1 = 0.f, blin = 0.f;
    if (stage == 2 && tid >= W5) {                 // final linear lives on helper wave
        int lane = tid - W5;
        wl0 = W_lin[lane];
        wl1 = (lane < HH-64) ? W_lin[64 + lane] : 0.0f;
        blin = b_lin[0];
    }

    __syncthreads();

    // ---- prologue (helper): xbuf[0] = x(0); xr = x(1) in regs ----
    float xr0 = 0.f, xr1 = 0.f;
    unsigned cin = 0, cons = 0;
    if (tid >= W5) {
        const int lane = tid - W5;
        if (stage == 0) {
            xbuf[0][lane] = seasons[lane];
            if (lane < HH-64) xbuf[0][64+lane] = seasons[64+lane];
            xr0 = seasons[HH + lane];
            if (lane < HH-64) xr1 = seasons[HH + 64 + lane];
        } else {
            do { cin = __hip_atomic_load(cnt_in, __ATOMIC_ACQUIRE, __HIP_MEMORY_SCOPE_AGENT); }
            while (cin < 2u);
            xbuf[0][lane] = __hip_atomic_load(ring_in + lane, __ATOMIC_RELAXED, __HIP_MEMORY_SCOPE_AGENT);
            if (lane < HH-64)
                xbuf[0][64+lane] = __hip_atomic_load(ring_in + 64 + lane, __ATOMIC_RELAXED, __HIP_MEMORY_SCOPE_AGENT);
            const float* rs = ring_in + (size_t)(1 % C) * SLOT;
            xr0 = __hip_atomic_load(rs + lane, __ATOMIC_RELAXED, __HIP_MEMORY_SCOPE_AGENT);
            if (lane < HH-64)
                xr1 = __hip_atomic_load(rs + 64 + lane, __ATOMIC_RELAXED, __HIP_MEMORY_SCOPE_AGENT);
        }
    }
    __syncthreads();

    float c = 0.0f;            // persistent cell state (tid < 74)
    float pf = 0.0f;           // L2 touch-prefetch sink

    for (int t = 0; t < TT; ++t) {
        // ================= Phase A =================
        if (isRowT) {
            // even lanes read float4s [0..9], odd lanes [10..19]: 160B apart ->
            // disjoint bank groups, conflict-free 2-address broadcast
            const float4* xv = ((const float4*)xbuf[t & 1]) + half*(KH/4);
            const float4* hv = ((const float4*)hbuf)        + half*(KH/4);
            float a0 = bias, a1 = 0.f, a2 = 0.f, a3 = 0.f;
            #pragma unroll
            for (int k = 0; k < KH/4; ++k) {
                float4 x4 = xv[k];
                a0 += wih[4*k+0] * x4.x;
                a1 += wih[4*k+1] * x4.y;
                a2 += wih[4*k+2] * x4.z;
                a3 += wih[4*k+3] * x4.w;
            }
            #pragma unroll
            for (int k = 0; k < KH/4; ++k) {
                float4 h4 = hv[k];
                a0 += whh[4*k+0] * h4.x;
                a1 += whh[4*k+1] * h4.y;
                a2 += whh[4*k+2] * h4.z;
                a3 += whh[4*k+3] * h4.w;
            }
            float p = (a0 + a1) + (a2 + a3);
            p += __shfl_xor(p, 1, 64);                       // combine K-halves
            float s = __builtin_amdgcn_rcpf(1.0f + __expf(-p));
            const bool isG = (row >= 2*HH) && (row < 3*HH);  // tanh = 2*sigm(2x)-1
            float g = isG ? fmaf(2.0f, s, -1.0f) : s;
            if (half == 0 && row < G4) gbuf[row] = g;
        } else {
            const int lane = tid - W5;
            // ---- ring store h(t-1) + publish (stages 0,1); linear (stage 2) ----
            if (t > 0) {
                if (stage < 2) {
                    float h0 = hbuf[lane];
                    float h1 = (lane < HH-64) ? hbuf[64+lane] : 0.0f;
                    while ((long)t - (long)cons > (long)(C - 8))     // flow control (rare)
                        cons = __hip_atomic_load(cnt_down, __ATOMIC_RELAXED, __HIP_MEMORY_SCOPE_AGENT);
                    float* rs = ring_out + (size_t)((t-1) % C) * SLOT;
                    __hip_atomic_store(rs + lane, h0, __ATOMIC_RELAXED, __HIP_MEMORY_SCOPE_AGENT);
                    if (lane < HH-64)
                        __hip_atomic_store(rs + 64 + lane, h1, __ATOMIC_RELAXED, __HIP_MEMORY_SCOPE_AGENT);
                    if (lane == 0)   // release waits this wave's stores -> visible first
                        __hip_atomic_store(cnt_out, (unsigned)t, __ATOMIC_RELEASE, __HIP_MEMORY_SCOPE_AGENT);
                } else {
                    if (lane == 0)   // progress only (stage1 flow control)
                        __hip_atomic_store(cnt_out, (unsigned)t, __ATOMIC_RELAXED, __HIP_MEMORY_SCOPE_AGENT);
                    float p = wl0 * hbuf[lane];
                    if (lane < HH-64) p += wl1 * hbuf[64 + lane];
                    #pragma unroll
                    for (int m = 32; m >= 1; m >>= 1)
                        p += __shfl_xor(p, m, 64);
                    if (lane == 0) out[t-1] = fmaxf(p + blin, 0.0f);
                }
            }
            // ---- write x(t+1) from regs (loaded one full step ago) ----
            const int nb = (t + 1) & 1;
            xbuf[nb][lane] = xr0;
            if (lane < HH-64) xbuf[nb][64+lane] = xr1;
            // ---- issue loads for x(t+2): latency spans a whole step ----
            if (t + 2 < TT) {
                if (stage == 0) {
                    const float* xs = seasons + (size_t)(t+2) * HH;
                    xr0 = xs[lane];
                    if (lane < HH-64) xr1 = xs[64+lane];
                    if (t + 16 < TT) pf += seasons[(size_t)(t+16)*HH + lane];
                } else {
                    if (cin < (unsigned)(t + 3)) {
                        do { cin = __hip_atomic_load(cnt_in, __ATOMIC_ACQUIRE, __HIP_MEMORY_SCOPE_AGENT); }
                        while (cin < (unsigned)(t + 3));
                    }
                    const float* rs2 = ring_in + (size_t)((t+2) % C) * SLOT;
                    xr0 = __hip_atomic_load(rs2 + lane, __ATOMIC_RELAXED, __HIP_MEMORY_SCOPE_AGENT);
                    if (lane < HH-64)
                        xr1 = __hip_atomic_load(rs2 + 64 + lane, __ATOMIC_RELAXED, __HIP_MEMORY_SCOPE_AGENT);
                    cin = __hip_atomic_load(cnt_in, __ATOMIC_RELAXED, __HIP_MEMORY_SCOPE_AGENT);
                }
            }
        }
        __syncthreads();   // barrier1: gates ready, x(t+1) staged

        // ================= Phase B =================
        if (tid < HH) {
            float iv = gbuf[tid];
            float fv = gbuf[HH + tid];
            float gv = gbuf[2*HH + tid];
            float ov = gbuf[3*HH + tid];
            c = fmaf(fv, c, iv * gv);
            float e  = __expf(-2.0f * fabsf(c));             // overflow-safe tanh
            float th = copysignf((1.0f - e) * __builtin_amdgcn_rcpf(1.0f + e), c);
            hbuf[tid] = ov * th;
        }
        __syncthreads();   // barrier2: h(t) ready
    }

    // ---- epilogue: h(TT-1) ----
    if (tid >= W5) {
        const int lane = tid - W5;
        if (stage < 2) {
            float h0 = hbuf[lane];
            float h1 = (lane < HH-64) ? hbuf[64+lane] : 0.0f;
            float* rs = ring_out + (size_t)((TT-1) % C) * SLOT;
            __hip_atomic_store(rs + lane, h0, __ATOMIC_RELAXED, __HIP_MEMORY_SCOPE_AGENT);
            if (lane < HH-64)
                __hip_atomic_store(rs + 64 + lane, h1, __ATOMIC_RELAXED, __HIP_MEMORY_SCOPE_AGENT);
            if (lane == 0)
                __hip_atomic_store(cnt_out, (unsigned)TT, __ATOMIC_RELEASE, __HIP_MEMORY_SCOPE_AGENT);
        } else {
            float p = wl0 * hbuf[lane];
            if (lane < HH-64) p += wl1 * hbuf[64 + lane];
            #pragma unroll
            for (int m = 32; m >= 1; m >>= 1)
                p += __shfl_xor(p, m, 64);
            if (lane == 0) out[TT-1] = fmaxf(p + blin, 0.0f);
        }
    }
    asm volatile("" :: "v"(pf));   // keep prefetch sum live
}

extern "C" void kernel_launch(void* const* d_in, const int* in_sizes, int n_in,
                              void* d_out, int out_size, void* d_ws, size_t ws_size,
                              hipStream_t stream)
{
    (void)in_sizes; (void)n_in; (void)out_size;
    const float* seasons = (const float*)d_in[0];
    const float* W_ih  = (const float*)d_in[1];
    const float* W_hh  = (const float*)d_in[2];
    const float* b_ih  = (const float*)d_in[3];
    const float* b_hh  = (const float*)d_in[4];
    const float* W_lin = (const float*)d_in[5];
    const float* b_lin = (const float*)d_in[6];
    float* out = (float*)d_out;

    unsigned* ctrl = (unsigned*)d_ws;
    float* ring0 = (float*)((char*)d_ws + 1024);
    long avail  = (long)ws_size - 1024;
    long cslots = avail / (long)(2 * SLOT * sizeof(float));
    int  C = (int)(cslots < TT ? cslots : TT);
    if (C > 2048) C = 2048;        // keep rings cache-resident (round2 wrote ~60MB HBM)
    if (C < 16)   C = 16;
    float* ring1 = ring0 + (size_t)C * SLOT;

    hipLaunchKernelGGL(init_ctrl, dim3(1), dim3(128), 0, stream, ctrl);
    hipLaunchKernelGGL(lstm_pipe, dim3(3), dim3(NT), 0, stream,
                       seasons, W_ih, W_hh, b_ih, b_hh, W_lin, b_lin,
                       out, ctrl, ring0, ring1, C);
}